// Round 5
// baseline (831.898 us; speedup 1.0000x reference)
//
#include <hip/hip_runtime.h>
#include <math.h>

#define NNODES 20000
#define NEDGES 640000
#define NS 128
#define ESZ 20
#define FW 384
#define CUT 5.0f
#define PI_F 3.14159265358979323846f
#define TM 32  // nodes per block in node_mlp part

#define MLP_BLOCKS (NNODES / TM)            // 625
#define HIST_BLOCKS ((NEDGES + 255) / 256)  // 2500

// -------- fused: node MLP (blocks [0,625)) + dst histogram (blocks [625,3125)) --------
__global__ __launch_bounds__(256) void prep(
    const float* __restrict__ ns, const float* __restrict__ W1,
    const float* __restrict__ b1, const float* __restrict__ W2,
    const float* __restrict__ b2, float* __restrict__ so,
    const int* __restrict__ edges, int* __restrict__ cnt) {
  __shared__ float in_s[TM][NS];   // 16 KB
  __shared__ float hid_s[TM][NS];  // 16 KB

  if (blockIdx.x >= MLP_BLOCKS) {
    // ---- histogram part ----
    const int e = (blockIdx.x - MLP_BLOCKS) * 256 + threadIdx.x;
    if (e < NEDGES) atomicAdd(&cnt[edges[2 * e + 1]], 1);
    return;
  }

  // ---- node MLP part: so = silu(ns@W1+b1)@W2+b2 for 32 nodes ----
  const int t = threadIdx.x;
  const int n0 = blockIdx.x * TM;
  {
    const float4* src4 = (const float4*)(ns + (size_t)n0 * NS);
    float4* dst4 = (float4*)in_s;
    for (int idx = t; idx < TM * NS / 4; idx += 256) dst4[idx] = src4[idx];
  }
  __syncthreads();
  const int j = t & 127;
  const int half = t >> 7;
  {
    float acc[16];
#pragma unroll
    for (int m = 0; m < 16; ++m) acc[m] = b1[j];
    for (int k = 0; k < NS; k += 4) {
      const float w0 = W1[(k + 0) * NS + j];
      const float w1 = W1[(k + 1) * NS + j];
      const float w2 = W1[(k + 2) * NS + j];
      const float w3 = W1[(k + 3) * NS + j];
#pragma unroll
      for (int m = 0; m < 16; ++m) {
        const float4 iv = *(const float4*)&in_s[half * 16 + m][k];
        acc[m] = fmaf(iv.x, w0, acc[m]);
        acc[m] = fmaf(iv.y, w1, acc[m]);
        acc[m] = fmaf(iv.z, w2, acc[m]);
        acc[m] = fmaf(iv.w, w3, acc[m]);
      }
    }
#pragma unroll
    for (int m = 0; m < 16; ++m) {
      const float a = acc[m];
      hid_s[half * 16 + m][j] = a / (1.0f + __expf(-a));
    }
  }
  __syncthreads();
  {
    float o0[16], o1[16], o2[16];
    const float bb0 = b2[j], bb1 = b2[j + NS], bb2 = b2[j + 2 * NS];
#pragma unroll
    for (int m = 0; m < 16; ++m) { o0[m] = bb0; o1[m] = bb1; o2[m] = bb2; }
    for (int k = 0; k < NS; k += 4) {
      float wa[4], wb[4], wc[4];
#pragma unroll
      for (int kk = 0; kk < 4; ++kk) {
        wa[kk] = W2[(k + kk) * FW + j];
        wb[kk] = W2[(k + kk) * FW + j + NS];
        wc[kk] = W2[(k + kk) * FW + j + 2 * NS];
      }
#pragma unroll
      for (int m = 0; m < 16; ++m) {
        const float4 hv = *(const float4*)&hid_s[half * 16 + m][k];
        o0[m] = fmaf(hv.x, wa[0], o0[m]); o0[m] = fmaf(hv.y, wa[1], o0[m]);
        o0[m] = fmaf(hv.z, wa[2], o0[m]); o0[m] = fmaf(hv.w, wa[3], o0[m]);
        o1[m] = fmaf(hv.x, wb[0], o1[m]); o1[m] = fmaf(hv.y, wb[1], o1[m]);
        o1[m] = fmaf(hv.z, wb[2], o1[m]); o1[m] = fmaf(hv.w, wb[3], o1[m]);
        o2[m] = fmaf(hv.x, wc[0], o2[m]); o2[m] = fmaf(hv.y, wc[1], o2[m]);
        o2[m] = fmaf(hv.z, wc[2], o2[m]); o2[m] = fmaf(hv.w, wc[3], o2[m]);
      }
    }
#pragma unroll
    for (int m = 0; m < 16; ++m) {
      const size_t row = (size_t)(n0 + half * 16 + m) * FW;
      so[row + j] = o0[m];
      so[row + j + NS] = o1[m];
      so[row + j + 2 * NS] = o2[m];
    }
  }
}

__global__ __launch_bounds__(256) void zero_cnt(int* __restrict__ cnt) {
  const int i = blockIdx.x * 256 + threadIdx.x;
  if (i < NNODES) cnt[i] = 0;
}

__global__ __launch_bounds__(1024) void scan_counts(const int* __restrict__ cnt,
                                                    int* __restrict__ offsets,
                                                    int* __restrict__ cursor) {
  __shared__ int psum[1024];
  const int t = threadIdx.x;
  const int base = t * 20;
  int local[20];
  int s = 0;
#pragma unroll
  for (int k = 0; k < 20; ++k) {
    const int idx = base + k;
    const int v = (idx < NNODES) ? cnt[idx] : 0;
    local[k] = s;
    s += v;
  }
  psum[t] = s;
  __syncthreads();
  for (int off = 1; off < 1024; off <<= 1) {
    const int v = (t >= off) ? psum[t - off] : 0;
    __syncthreads();
    psum[t] += v;
    __syncthreads();
  }
  const int pre = (t > 0) ? psum[t - 1] : 0;
#pragma unroll
  for (int k = 0; k < 20; ++k) {
    const int idx = base + k;
    if (idx < NNODES) {
      offsets[idx] = pre + local[k];
      cursor[idx] = pre + local[k];
    }
  }
  if (t == 1023) offsets[NNODES] = psum[1023];
}

__global__ __launch_bounds__(256) void scatter_edges(const int* __restrict__ edges,
                                                     int* __restrict__ cursor,
                                                     int* __restrict__ elist) {
  const int e = blockIdx.x * 256 + threadIdx.x;
  if (e < NEDGES) {
    const int pos = atomicAdd(&cursor[edges[2 * e + 1]], 1);
    elist[pos] = e;
  }
}

// -------- per-dst accumulation: 256 thr = 2 edge-groups of 128, no atomics --------
__global__ __launch_bounds__(256) void accum(
    const int* __restrict__ elist, const int* __restrict__ offsets,
    const int* __restrict__ edges, const float* __restrict__ edge_state,
    const float* __restrict__ edge_vector, const float* __restrict__ edge_distance,
    const float* __restrict__ Wf, const float* __restrict__ bf,
    const float* __restrict__ so, const float* __restrict__ ns,
    const float* __restrict__ nsv, float* __restrict__ out0,
    float* __restrict__ out1) {
  __shared__ float red[4][NS];  // group-1 partials: accs, av0, av1, av2
  const int n = blockIdx.x;
  const int t = threadIdx.x;
  const int j = t & 127;   // column
  const int g = t >> 7;    // edge group 0/1
  const int beg = offsets[n];
  const int end = offsets[n + 1];

  // W_filter columns register-resident across all edges
  float wf0[ESZ], wf1[ESZ], wf2[ESZ];
#pragma unroll
  for (int k = 0; k < ESZ; ++k) {
    wf0[k] = Wf[k * FW + j];
    wf1[k] = Wf[k * FW + j + NS];
    wf2[k] = Wf[k * FW + j + 2 * NS];
  }
  const float bf0 = bf[j], bf1 = bf[j + NS], bf2 = bf[j + 2 * NS];

  float accs = 0.0f, av0 = 0.0f, av1 = 0.0f, av2 = 0.0f;

  for (int i = beg + g; i < end; i += 2) {
    const int e = __builtin_amdgcn_readfirstlane(elist[i]);
    const int src = __builtin_amdgcn_readfirstlane(edges[2 * e]);

    const float d = edge_distance[e];
    const float cut = (d < CUT) ? 0.5f * (__cosf(PI_F * d * (1.0f / CUT)) + 1.0f) : 0.0f;

    const float ev0 = edge_vector[3 * e + 0];
    const float ev1 = edge_vector[3 * e + 1];
    const float ev2 = edge_vector[3 * e + 2];
    const float nrm = sqrtf(ev0 * ev0 + ev1 * ev1 + ev2 * ev2);
    const float inv = 1.0f / fmaxf(nrm, 1e-12f);
    const float env0 = ev0 * inv, env1 = ev1 * inv, env2 = ev2 * inv;

    const float* __restrict__ esp = edge_state + (size_t)e * ESZ;
    float fo0 = bf0, fo1 = bf1, fo2 = bf2;
#pragma unroll
    for (int k = 0; k < ESZ; ++k) {
      const float es = esp[k];
      fo0 = fmaf(es, wf0[k], fo0);
      fo1 = fmaf(es, wf1[k], fo1);
      fo2 = fmaf(es, wf2[k], fo2);
    }

    const float* __restrict__ sop = so + (size_t)src * FW;
    fo0 *= cut * sop[j];
    fo1 *= cut * sop[j + NS];
    fo2 *= cut * sop[j + 2 * NS];

    accs = fmaf(ns[(size_t)src * NS + j], fo2, accs);
    const float* __restrict__ nvp = nsv + (size_t)src * 3 * NS;
    av0 = fmaf(nvp[j], fo0, av0);           av0 = fmaf(fo1, env0, av0);
    av1 = fmaf(nvp[NS + j], fo0, av1);      av1 = fmaf(fo1, env1, av1);
    av2 = fmaf(nvp[2 * NS + j], fo0, av2);  av2 = fmaf(fo1, env2, av2);
  }

  // cross-group reduce + output (residual fused)
  if (g == 1) {
    red[0][j] = accs; red[1][j] = av0; red[2][j] = av1; red[3][j] = av2;
  }
  __syncthreads();
  if (g == 0) {
    accs += red[0][j]; av0 += red[1][j]; av1 += red[2][j]; av2 += red[3][j];
    out0[(size_t)n * NS + j] = ns[(size_t)n * NS + j] + accs;
    float* __restrict__ o1 = out1 + (size_t)n * 3 * NS;
    const float* __restrict__ nvd = nsv + (size_t)n * 3 * NS;
    o1[j] = nvd[j] + av0;
    o1[NS + j] = nvd[NS + j] + av1;
    o1[2 * NS + j] = nvd[2 * NS + j] + av2;
  }
}

extern "C" void kernel_launch(void* const* d_in, const int* in_sizes, int n_in,
                              void* d_out, int out_size, void* d_ws, size_t ws_size,
                              hipStream_t stream) {
  const float* node_state_scalar = (const float*)d_in[0];
  const float* node_state_vector = (const float*)d_in[1];
  const float* edge_state        = (const float*)d_in[2];
  const float* edge_vector       = (const float*)d_in[3];
  const float* edge_distance     = (const float*)d_in[4];
  const int*   edges             = (const int*)d_in[5];
  const float* W_filter          = (const float*)d_in[6];
  const float* b_filter          = (const float*)d_in[7];
  const float* W1                = (const float*)d_in[8];
  const float* b1                = (const float*)d_in[9];
  const float* W2                = (const float*)d_in[10];
  const float* b2                = (const float*)d_in[11];

  float* out0 = (float*)d_out;                       // (20000,128)
  float* out1 = (float*)d_out + (size_t)NNODES * NS; // (20000,3,128)

  // workspace layout
  float* so    = (float*)d_ws;                        // 20000*384 floats
  int* elist   = (int*)(so + (size_t)NNODES * FW);    // 640000
  int* offsets = elist + NEDGES;                      // 20001
  int* cursor  = offsets + (NNODES + 1);              // 20000
  int* cnt     = cursor + NNODES;                     // 20000

  zero_cnt<<<(NNODES + 255) / 256, 256, 0, stream>>>(cnt);
  // fused node-MLP + dst-histogram
  prep<<<MLP_BLOCKS + HIST_BLOCKS, 256, 0, stream>>>(
      node_state_scalar, W1, b1, W2, b2, so, edges, cnt);
  scan_counts<<<1, 1024, 0, stream>>>(cnt, offsets, cursor);
  scatter_edges<<<(NEDGES + 255) / 256, 256, 0, stream>>>(edges, cursor, elist);
  // per-dst accumulation, residual fused
  accum<<<NNODES, 256, 0, stream>>>(elist, offsets, edges, edge_state, edge_vector,
                                    edge_distance, W_filter, b_filter, so,
                                    node_state_scalar, node_state_vector,
                                    out0, out1);
}

// Round 6
// 586.763 us; speedup vs baseline: 1.4178x; 1.4178x over previous
//
#include <hip/hip_runtime.h>
#include <math.h>

#define NNODES 20000
#define NEDGES 640000
#define NS 128
#define ESZ 20
#define FW 384
#define CUT 5.0f
#define PI_F 3.14159265358979323846f
#define TM 32  // nodes per block in node_mlp part

#define MLP_BLOCKS (NNODES / TM)            // 625
#define HIST_BLOCKS ((NEDGES + 255) / 256)  // 2500
#define RSTRIDE 8                           // dwords per sorted edge record (32 B)

// -------- fused: node MLP (blocks [0,625)) + dst histogram (blocks [625,3125)) --------
__global__ __launch_bounds__(256) void prep(
    const float* __restrict__ ns, const float* __restrict__ W1,
    const float* __restrict__ b1, const float* __restrict__ W2,
    const float* __restrict__ b2, float* __restrict__ so,
    const int* __restrict__ edges, int* __restrict__ cnt) {
  __shared__ float in_s[TM][NS];   // 16 KB
  __shared__ float hid_s[TM][NS];  // 16 KB

  if (blockIdx.x >= MLP_BLOCKS) {
    const int e = (blockIdx.x - MLP_BLOCKS) * 256 + threadIdx.x;
    if (e < NEDGES) atomicAdd(&cnt[edges[2 * e + 1]], 1);
    return;
  }

  const int t = threadIdx.x;
  const int n0 = blockIdx.x * TM;
  {
    const float4* src4 = (const float4*)(ns + (size_t)n0 * NS);
    float4* dst4 = (float4*)in_s;
    for (int idx = t; idx < TM * NS / 4; idx += 256) dst4[idx] = src4[idx];
  }
  __syncthreads();
  const int j = t & 127;
  const int half = t >> 7;
  {
    float acc[16];
#pragma unroll
    for (int m = 0; m < 16; ++m) acc[m] = b1[j];
    for (int k = 0; k < NS; k += 4) {
      const float w0 = W1[(k + 0) * NS + j];
      const float w1 = W1[(k + 1) * NS + j];
      const float w2 = W1[(k + 2) * NS + j];
      const float w3 = W1[(k + 3) * NS + j];
#pragma unroll
      for (int m = 0; m < 16; ++m) {
        const float4 iv = *(const float4*)&in_s[half * 16 + m][k];
        acc[m] = fmaf(iv.x, w0, acc[m]);
        acc[m] = fmaf(iv.y, w1, acc[m]);
        acc[m] = fmaf(iv.z, w2, acc[m]);
        acc[m] = fmaf(iv.w, w3, acc[m]);
      }
    }
#pragma unroll
    for (int m = 0; m < 16; ++m) {
      const float a = acc[m];
      hid_s[half * 16 + m][j] = a / (1.0f + __expf(-a));
    }
  }
  __syncthreads();
  {
    float o0[16], o1[16], o2[16];
    const float bb0 = b2[j], bb1 = b2[j + NS], bb2 = b2[j + 2 * NS];
#pragma unroll
    for (int m = 0; m < 16; ++m) { o0[m] = bb0; o1[m] = bb1; o2[m] = bb2; }
    for (int k = 0; k < NS; k += 4) {
      float wa[4], wb[4], wc[4];
#pragma unroll
      for (int kk = 0; kk < 4; ++kk) {
        wa[kk] = W2[(k + kk) * FW + j];
        wb[kk] = W2[(k + kk) * FW + j + NS];
        wc[kk] = W2[(k + kk) * FW + j + 2 * NS];
      }
#pragma unroll
      for (int m = 0; m < 16; ++m) {
        const float4 hv = *(const float4*)&hid_s[half * 16 + m][k];
        o0[m] = fmaf(hv.x, wa[0], o0[m]); o0[m] = fmaf(hv.y, wa[1], o0[m]);
        o0[m] = fmaf(hv.z, wa[2], o0[m]); o0[m] = fmaf(hv.w, wa[3], o0[m]);
        o1[m] = fmaf(hv.x, wb[0], o1[m]); o1[m] = fmaf(hv.y, wb[1], o1[m]);
        o1[m] = fmaf(hv.z, wb[2], o1[m]); o1[m] = fmaf(hv.w, wb[3], o1[m]);
        o2[m] = fmaf(hv.x, wc[0], o2[m]); o2[m] = fmaf(hv.y, wc[1], o2[m]);
        o2[m] = fmaf(hv.z, wc[2], o2[m]); o2[m] = fmaf(hv.w, wc[3], o2[m]);
      }
    }
#pragma unroll
    for (int m = 0; m < 16; ++m) {
      const size_t row = (size_t)(n0 + half * 16 + m) * FW;
      so[row + j] = o0[m];
      so[row + j + NS] = o1[m];
      so[row + j + 2 * NS] = o2[m];
    }
  }
}

__global__ __launch_bounds__(256) void zero_cnt(int* __restrict__ cnt) {
  const int i = blockIdx.x * 256 + threadIdx.x;
  if (i < NNODES) cnt[i] = 0;
}

__global__ __launch_bounds__(1024) void scan_counts(const int* __restrict__ cnt,
                                                    int* __restrict__ offsets,
                                                    int* __restrict__ cursor) {
  __shared__ int psum[1024];
  const int t = threadIdx.x;
  const int base = t * 20;
  int local[20];
  int s = 0;
#pragma unroll
  for (int k = 0; k < 20; ++k) {
    const int idx = base + k;
    const int v = (idx < NNODES) ? cnt[idx] : 0;
    local[k] = s;
    s += v;
  }
  psum[t] = s;
  __syncthreads();
  for (int off = 1; off < 1024; off <<= 1) {
    const int v = (t >= off) ? psum[t - off] : 0;
    __syncthreads();
    psum[t] += v;
    __syncthreads();
  }
  const int pre = (t > 0) ? psum[t - 1] : 0;
#pragma unroll
  for (int k = 0; k < 20; ++k) {
    const int idx = base + k;
    if (idx < NNODES) {
      offsets[idx] = pre + local[k];
      cursor[idx] = pre + local[k];
    }
  }
  if (t == 1023) offsets[NNODES] = psum[1023];
}

// -------- scatter: build sorted 32 B edge records {src, e, cut, env0..2} --------
__global__ __launch_bounds__(256) void scatter_edges(
    const int* __restrict__ edges, const float* __restrict__ edge_distance,
    const float* __restrict__ edge_vector, int* __restrict__ cursor,
    float* __restrict__ recf) {
  const int e = blockIdx.x * 256 + threadIdx.x;
  if (e >= NEDGES) return;
  const int src = edges[2 * e];
  const int dst = edges[2 * e + 1];
  const int pos = atomicAdd(&cursor[dst], 1);

  const float d = edge_distance[e];
  const float cut = (d < CUT) ? 0.5f * (__cosf(PI_F * d * (1.0f / CUT)) + 1.0f) : 0.0f;
  const float ev0 = edge_vector[3 * e + 0];
  const float ev1 = edge_vector[3 * e + 1];
  const float ev2 = edge_vector[3 * e + 2];
  const float inv = 1.0f / fmaxf(sqrtf(ev0 * ev0 + ev1 * ev1 + ev2 * ev2), 1e-12f);

  float* __restrict__ r = recf + (size_t)pos * RSTRIDE;
  ((int*)r)[0] = src;
  ((int*)r)[1] = e;
  r[2] = cut;
  r[3] = ev0 * inv;
  r[4] = ev1 * inv;
  r[5] = ev2 * inv;
}

// -------- per-dst accumulation over sorted records (no atomics, no indirection) --------
__global__ __launch_bounds__(128) void accum(
    const float* __restrict__ recf, const int* __restrict__ offsets,
    const float* __restrict__ edge_state, const float* __restrict__ Wf,
    const float* __restrict__ bf, const float* __restrict__ so,
    const float* __restrict__ ns, const float* __restrict__ nsv,
    float* __restrict__ out0, float* __restrict__ out1) {
  const int n = blockIdx.x;
  const int j = threadIdx.x;
  const int beg = offsets[n];
  const int end = offsets[n + 1];

  float wf0[ESZ], wf1[ESZ], wf2[ESZ];
#pragma unroll
  for (int k = 0; k < ESZ; ++k) {
    wf0[k] = Wf[k * FW + j];
    wf1[k] = Wf[k * FW + j + NS];
    wf2[k] = Wf[k * FW + j + 2 * NS];
  }
  const float bf0 = bf[j], bf1 = bf[j + NS], bf2 = bf[j + 2 * NS];

  float accs = 0.0f, av0 = 0.0f, av1 = 0.0f, av2 = 0.0f;

#pragma unroll 2
  for (int i = beg; i < end; ++i) {
    const float* __restrict__ r = recf + (size_t)i * RSTRIDE;
    const int src = __builtin_amdgcn_readfirstlane(((const int*)r)[0]);
    const int e   = __builtin_amdgcn_readfirstlane(((const int*)r)[1]);
    const float cut = r[2];
    const float env0 = r[3], env1 = r[4], env2 = r[5];

    const float* __restrict__ esp = edge_state + (size_t)e * ESZ;
    float fo0 = bf0, fo1 = bf1, fo2 = bf2;
#pragma unroll
    for (int k = 0; k < ESZ; ++k) {
      const float es = esp[k];
      fo0 = fmaf(es, wf0[k], fo0);
      fo1 = fmaf(es, wf1[k], fo1);
      fo2 = fmaf(es, wf2[k], fo2);
    }

    const float* __restrict__ sop = so + (size_t)src * FW;
    fo0 *= cut * sop[j];
    fo1 *= cut * sop[j + NS];
    fo2 *= cut * sop[j + 2 * NS];

    accs = fmaf(ns[(size_t)src * NS + j], fo2, accs);
    const float* __restrict__ nvp = nsv + (size_t)src * 3 * NS;
    av0 = fmaf(nvp[j], fo0, av0);           av0 = fmaf(fo1, env0, av0);
    av1 = fmaf(nvp[NS + j], fo0, av1);      av1 = fmaf(fo1, env1, av1);
    av2 = fmaf(nvp[2 * NS + j], fo0, av2);  av2 = fmaf(fo1, env2, av2);
  }

  out0[(size_t)n * NS + j] = ns[(size_t)n * NS + j] + accs;
  float* __restrict__ o1 = out1 + (size_t)n * 3 * NS;
  const float* __restrict__ nvd = nsv + (size_t)n * 3 * NS;
  o1[j] = nvd[j] + av0;
  o1[NS + j] = nvd[NS + j] + av1;
  o1[2 * NS + j] = nvd[2 * NS + j] + av2;
}

extern "C" void kernel_launch(void* const* d_in, const int* in_sizes, int n_in,
                              void* d_out, int out_size, void* d_ws, size_t ws_size,
                              hipStream_t stream) {
  const float* node_state_scalar = (const float*)d_in[0];
  const float* node_state_vector = (const float*)d_in[1];
  const float* edge_state        = (const float*)d_in[2];
  const float* edge_vector       = (const float*)d_in[3];
  const float* edge_distance     = (const float*)d_in[4];
  const int*   edges             = (const int*)d_in[5];
  const float* W_filter          = (const float*)d_in[6];
  const float* b_filter          = (const float*)d_in[7];
  const float* W1                = (const float*)d_in[8];
  const float* b1                = (const float*)d_in[9];
  const float* W2                = (const float*)d_in[10];
  const float* b2                = (const float*)d_in[11];

  float* out0 = (float*)d_out;                       // (20000,128)
  float* out1 = (float*)d_out + (size_t)NNODES * NS; // (20000,3,128)

  // workspace layout (~52 MB)
  float* so    = (float*)d_ws;                         // 20000*384 floats
  float* recf  = so + (size_t)NNODES * FW;             // 640000*8 floats (32 B records)
  int* offsets = (int*)(recf + (size_t)NEDGES * RSTRIDE); // 20001
  int* cursor  = offsets + (NNODES + 1);               // 20000
  int* cnt     = cursor + NNODES;                      // 20000

  zero_cnt<<<(NNODES + 255) / 256, 256, 0, stream>>>(cnt);
  prep<<<MLP_BLOCKS + HIST_BLOCKS, 256, 0, stream>>>(
      node_state_scalar, W1, b1, W2, b2, so, edges, cnt);
  scan_counts<<<1, 1024, 0, stream>>>(cnt, offsets, cursor);
  scatter_edges<<<(NEDGES + 255) / 256, 256, 0, stream>>>(
      edges, edge_distance, edge_vector, cursor, recf);
  accum<<<NNODES, 128, 0, stream>>>(recf, offsets, edge_state, W_filter, b_filter,
                                    so, node_state_scalar, node_state_vector,
                                    out0, out1);
}

// Round 7
// 523.046 us; speedup vs baseline: 1.5905x; 1.1218x over previous
//
#include <hip/hip_runtime.h>
#include <math.h>

#define NNODES 20000
#define NEDGES 640000
#define NS 128
#define ESZ 20
#define FW 384
#define CUT 5.0f
#define PI_F 3.14159265358979323846f
#define TM 32

#define MLP_BLOCKS (NNODES / TM)            // 625
#define HIST_BLOCKS ((NEDGES + 255) / 256)  // 2500

typedef unsigned int uint;
typedef unsigned short ushort;

// f32 -> bf16 with round-to-nearest-even
static __device__ __forceinline__ ushort f2b(float f) {
  uint u = __float_as_uint(f);
  u += 0x7FFFu + ((u >> 16) & 1u);
  return (ushort)(u >> 16);
}
// bf16 (as ushort) -> f32, exact
static __device__ __forceinline__ float b2f(ushort v) {
  return __uint_as_float(((uint)v) << 16);
}

// -------- fused: node MLP + P/V/S1 bf16 production (blocks [0,625)) + dst histogram --------
__global__ __launch_bounds__(256) void prep(
    const float* __restrict__ ns, const float* __restrict__ nsv,
    const float* __restrict__ W1, const float* __restrict__ b1,
    const float* __restrict__ W2, const float* __restrict__ b2,
    ushort* __restrict__ Pb, ushort* __restrict__ Vb, ushort* __restrict__ S1b,
    const int* __restrict__ edges, int* __restrict__ cnt) {
  __shared__ float in_s[TM][NS];   // 16 KB
  __shared__ float hid_s[TM][NS];  // 16 KB

  if (blockIdx.x >= MLP_BLOCKS) {
    const int e = (blockIdx.x - MLP_BLOCKS) * 256 + threadIdx.x;
    if (e < NEDGES) atomicAdd(&cnt[edges[2 * e + 1]], 1);
    return;
  }

  const int t = threadIdx.x;
  const int n0 = blockIdx.x * TM;
  {
    const float4* src4 = (const float4*)(ns + (size_t)n0 * NS);
    float4* dst4 = (float4*)in_s;
    for (int idx = t; idx < TM * NS / 4; idx += 256) dst4[idx] = src4[idx];
  }
  __syncthreads();
  const int j = t & 127;
  const int half = t >> 7;
  {
    float acc[16];
#pragma unroll
    for (int m = 0; m < 16; ++m) acc[m] = b1[j];
    for (int k = 0; k < NS; k += 4) {
      const float w0 = W1[(k + 0) * NS + j];
      const float w1 = W1[(k + 1) * NS + j];
      const float w2 = W1[(k + 2) * NS + j];
      const float w3 = W1[(k + 3) * NS + j];
#pragma unroll
      for (int m = 0; m < 16; ++m) {
        const float4 iv = *(const float4*)&in_s[half * 16 + m][k];
        acc[m] = fmaf(iv.x, w0, acc[m]);
        acc[m] = fmaf(iv.y, w1, acc[m]);
        acc[m] = fmaf(iv.z, w2, acc[m]);
        acc[m] = fmaf(iv.w, w3, acc[m]);
      }
    }
#pragma unroll
    for (int m = 0; m < 16; ++m) {
      const float a = acc[m];
      hid_s[half * 16 + m][j] = a / (1.0f + __expf(-a));
    }
  }
  __syncthreads();
  {
    float o0[16], o1[16], o2[16];
    const float bb0 = b2[j], bb1 = b2[j + NS], bb2 = b2[j + 2 * NS];
#pragma unroll
    for (int m = 0; m < 16; ++m) { o0[m] = bb0; o1[m] = bb1; o2[m] = bb2; }
    for (int k = 0; k < NS; k += 4) {
      float wa[4], wb[4], wc[4];
#pragma unroll
      for (int kk = 0; kk < 4; ++kk) {
        wa[kk] = W2[(k + kk) * FW + j];
        wb[kk] = W2[(k + kk) * FW + j + NS];
        wc[kk] = W2[(k + kk) * FW + j + 2 * NS];
      }
#pragma unroll
      for (int m = 0; m < 16; ++m) {
        const float4 hv = *(const float4*)&hid_s[half * 16 + m][k];
        o0[m] = fmaf(hv.x, wa[0], o0[m]); o0[m] = fmaf(hv.y, wa[1], o0[m]);
        o0[m] = fmaf(hv.z, wa[2], o0[m]); o0[m] = fmaf(hv.w, wa[3], o0[m]);
        o1[m] = fmaf(hv.x, wb[0], o1[m]); o1[m] = fmaf(hv.y, wb[1], o1[m]);
        o1[m] = fmaf(hv.z, wb[2], o1[m]); o1[m] = fmaf(hv.w, wb[3], o1[m]);
        o2[m] = fmaf(hv.x, wc[0], o2[m]); o2[m] = fmaf(hv.y, wc[1], o2[m]);
        o2[m] = fmaf(hv.z, wc[2], o2[m]); o2[m] = fmaf(hv.w, wc[3], o2[m]);
      }
    }
    // Emit gather-side arrays in bf16:
    //   P  = ns  * so2   (scalar-message source)
    //   V  = nsv * so0   (vector-message source, 3 comps)
    //   S1 = so1         (edge-vector gate)
#pragma unroll
    for (int m = 0; m < 16; ++m) {
      const int n = n0 + half * 16 + m;
      const float nsval = in_s[half * 16 + m][j];
      Pb[(size_t)n * NS + j]  = f2b(nsval * o2[m]);
      S1b[(size_t)n * NS + j] = f2b(o1[m]);
      const float* __restrict__ nvp = nsv + (size_t)n * 3 * NS;
      Vb[(size_t)n * 3 * NS + j]          = f2b(nvp[j] * o0[m]);
      Vb[(size_t)n * 3 * NS + NS + j]     = f2b(nvp[NS + j] * o0[m]);
      Vb[(size_t)n * 3 * NS + 2 * NS + j] = f2b(nvp[2 * NS + j] * o0[m]);
    }
  }
}

__global__ __launch_bounds__(256) void zero_cnt(int* __restrict__ cnt) {
  const int i = blockIdx.x * 256 + threadIdx.x;
  if (i < NNODES) cnt[i] = 0;
}

__global__ __launch_bounds__(1024) void scan_counts(const int* __restrict__ cnt,
                                                    int* __restrict__ offsets,
                                                    int* __restrict__ cursor) {
  __shared__ int psum[1024];
  const int t = threadIdx.x;
  const int base = t * 20;
  int local[20];
  int s = 0;
#pragma unroll
  for (int k = 0; k < 20; ++k) {
    const int idx = base + k;
    const int v = (idx < NNODES) ? cnt[idx] : 0;
    local[k] = s;
    s += v;
  }
  psum[t] = s;
  __syncthreads();
  for (int off = 1; off < 1024; off <<= 1) {
    const int v = (t >= off) ? psum[t - off] : 0;
    __syncthreads();
    psum[t] += v;
    __syncthreads();
  }
  const int pre = (t > 0) ? psum[t - 1] : 0;
#pragma unroll
  for (int k = 0; k < 20; ++k) {
    const int idx = base + k;
    if (idx < NNODES) {
      offsets[idx] = pre + local[k];
      cursor[idx] = pre + local[k];
    }
  }
  if (t == 1023) offsets[NNODES] = psum[1023];
}

// -------- scatter: 64 B sorted records {src, cut, env0..2, pad, bf16(cut*es)[20]} --------
__global__ __launch_bounds__(256) void scatter_edges(
    const int* __restrict__ edges, const float* __restrict__ edge_distance,
    const float* __restrict__ edge_vector, const float* __restrict__ edge_state,
    int* __restrict__ cursor, uint* __restrict__ rec) {
  const int e = blockIdx.x * 256 + threadIdx.x;
  if (e >= NEDGES) return;
  const int src = edges[2 * e];
  const int dst = edges[2 * e + 1];
  const int pos = atomicAdd(&cursor[dst], 1);

  const float d = edge_distance[e];
  const float cut = (d < CUT) ? 0.5f * (__cosf(PI_F * d * (1.0f / CUT)) + 1.0f) : 0.0f;
  const float ev0 = edge_vector[3 * e + 0];
  const float ev1 = edge_vector[3 * e + 1];
  const float ev2 = edge_vector[3 * e + 2];
  const float inv = 1.0f / fmaxf(sqrtf(ev0 * ev0 + ev1 * ev1 + ev2 * ev2), 1e-12f);

  uint* __restrict__ r = rec + (size_t)pos * 16;
  r[0] = (uint)src;
  r[1] = __float_as_uint(cut);
  r[2] = __float_as_uint(ev0 * inv);
  r[3] = __float_as_uint(ev1 * inv);
  r[4] = __float_as_uint(ev2 * inv);
  r[5] = 0u;
  const float* __restrict__ esp = edge_state + (size_t)e * ESZ;
#pragma unroll
  for (int k = 0; k < 10; ++k) {
    const uint lo = (uint)f2b(cut * esp[2 * k]);
    const uint hi = (uint)f2b(cut * esp[2 * k + 1]);
    r[6 + k] = lo | (hi << 16);
  }
}

// -------- per-dst accumulation: sequential records + bf16 node gathers --------
__global__ __launch_bounds__(128) void accum(
    const uint4* __restrict__ rec, const int* __restrict__ offsets,
    const float* __restrict__ Wf, const float* __restrict__ bf,
    const ushort* __restrict__ Pb, const ushort* __restrict__ Vb,
    const ushort* __restrict__ S1b, const float* __restrict__ ns,
    const float* __restrict__ nsv, float* __restrict__ out0,
    float* __restrict__ out1) {
  const int n = blockIdx.x;
  const int j = threadIdx.x;
  const int beg = offsets[n];
  const int end = offsets[n + 1];

  float wf0[ESZ], wf1[ESZ], wf2[ESZ];
#pragma unroll
  for (int k = 0; k < ESZ; ++k) {
    wf0[k] = Wf[k * FW + j];
    wf1[k] = Wf[k * FW + j + NS];
    wf2[k] = Wf[k * FW + j + 2 * NS];
  }
  const float bf0 = bf[j], bf1 = bf[j + NS], bf2 = bf[j + 2 * NS];

  float accs = 0.0f, av0 = 0.0f, av1 = 0.0f, av2 = 0.0f;

#pragma unroll 2
  for (int i = beg; i < end; ++i) {
    const uint4 ra = rec[(size_t)i * 4 + 0];  // src, cut, env0, env1
    const uint4 rb = rec[(size_t)i * 4 + 1];  // env2, pad, es01, es23
    const uint4 rc = rec[(size_t)i * 4 + 2];  // es4..es11
    const uint4 rd = rec[(size_t)i * 4 + 3];  // es12..es19
    const int src = __builtin_amdgcn_readfirstlane((int)ra.x);
    const float cut  = __uint_as_float(ra.y);
    const float env0 = __uint_as_float(ra.z);
    const float env1 = __uint_as_float(ra.w);
    const float env2 = __uint_as_float(rb.x);

    float fw0 = cut * bf0, fw1 = cut * bf1, fw2 = cut * bf2;
    const uint ew[10] = {rb.z, rb.w, rc.x, rc.y, rc.z, rc.w, rd.x, rd.y, rd.z, rd.w};
#pragma unroll
    for (int k = 0; k < 10; ++k) {
      const float elo = __uint_as_float(ew[k] << 16);
      const float ehi = __uint_as_float(ew[k] & 0xFFFF0000u);
      fw0 = fmaf(elo, wf0[2 * k], fw0); fw0 = fmaf(ehi, wf0[2 * k + 1], fw0);
      fw1 = fmaf(elo, wf1[2 * k], fw1); fw1 = fmaf(ehi, wf1[2 * k + 1], fw1);
      fw2 = fmaf(elo, wf2[2 * k], fw2); fw2 = fmaf(ehi, wf2[2 * k + 1], fw2);
    }

    const float P  = b2f(Pb[(size_t)src * NS + j]);
    const float S1 = b2f(S1b[(size_t)src * NS + j]);
    const ushort* __restrict__ vp = Vb + (size_t)src * 3 * NS + j;
    const float V0 = b2f(vp[0]);
    const float V1 = b2f(vp[NS]);
    const float V2 = b2f(vp[2 * NS]);

    accs = fmaf(P, fw2, accs);
    const float s1fw = S1 * fw1;
    av0 = fmaf(V0, fw0, av0); av0 = fmaf(env0, s1fw, av0);
    av1 = fmaf(V1, fw0, av1); av1 = fmaf(env1, s1fw, av1);
    av2 = fmaf(V2, fw0, av2); av2 = fmaf(env2, s1fw, av2);
  }

  out0[(size_t)n * NS + j] = ns[(size_t)n * NS + j] + accs;
  float* __restrict__ o1 = out1 + (size_t)n * 3 * NS;
  const float* __restrict__ nvd = nsv + (size_t)n * 3 * NS;
  o1[j] = nvd[j] + av0;
  o1[NS + j] = nvd[NS + j] + av1;
  o1[2 * NS + j] = nvd[2 * NS + j] + av2;
}

extern "C" void kernel_launch(void* const* d_in, const int* in_sizes, int n_in,
                              void* d_out, int out_size, void* d_ws, size_t ws_size,
                              hipStream_t stream) {
  const float* node_state_scalar = (const float*)d_in[0];
  const float* node_state_vector = (const float*)d_in[1];
  const float* edge_state        = (const float*)d_in[2];
  const float* edge_vector       = (const float*)d_in[3];
  const float* edge_distance     = (const float*)d_in[4];
  const int*   edges             = (const int*)d_in[5];
  const float* W_filter          = (const float*)d_in[6];
  const float* b_filter          = (const float*)d_in[7];
  const float* W1                = (const float*)d_in[8];
  const float* b1                = (const float*)d_in[9];
  const float* W2                = (const float*)d_in[10];
  const float* b2                = (const float*)d_in[11];

  float* out0 = (float*)d_out;
  float* out1 = (float*)d_out + (size_t)NNODES * NS;

  // workspace layout (~67 MB)
  char* w = (char*)d_ws;
  ushort* Pb  = (ushort*)w;                        w += (size_t)NNODES * NS * 2;      // 5.12 MB
  ushort* S1b = (ushort*)w;                        w += (size_t)NNODES * NS * 2;      // 5.12 MB
  ushort* Vb  = (ushort*)w;                        w += (size_t)NNODES * 3 * NS * 2;  // 15.36 MB
  uint*   rec = (uint*)w;                          w += (size_t)NEDGES * 64;          // 40.96 MB
  int* offsets = (int*)w;                          w += (NNODES + 1) * 4;
  int* cursor  = (int*)w;                          w += NNODES * 4;
  int* cnt     = (int*)w;

  zero_cnt<<<(NNODES + 255) / 256, 256, 0, stream>>>(cnt);
  prep<<<MLP_BLOCKS + HIST_BLOCKS, 256, 0, stream>>>(
      node_state_scalar, node_state_vector, W1, b1, W2, b2,
      Pb, Vb, S1b, edges, cnt);
  scan_counts<<<1, 1024, 0, stream>>>(cnt, offsets, cursor);
  scatter_edges<<<(NEDGES + 255) / 256, 256, 0, stream>>>(
      edges, edge_distance, edge_vector, edge_state, cursor, rec);
  accum<<<NNODES, 128, 0, stream>>>((const uint4*)rec, offsets, W_filter, b_filter,
                                    Pb, Vb, S1b, node_state_scalar,
                                    node_state_vector, out0, out1);
}

// Round 10
// 429.125 us; speedup vs baseline: 1.9386x; 1.2189x over previous
//
#include <hip/hip_runtime.h>
#include <math.h>

#define NNODES 20000
#define NEDGES 640000
#define NS 128
#define ESZ 20
#define FW 384
#define CUT 5.0f
#define PI_F 3.14159265358979323846f
#define TM 32

#define MLP_BLOCKS (NNODES / TM)            // 625
#define HIST_BLOCKS ((NEDGES + 255) / 256)  // 2500

typedef unsigned int uint;
typedef unsigned short ushort;
typedef _Float16 h2 __attribute__((ext_vector_type(2)));

// f32 -> bf16 round-to-nearest-even
static __device__ __forceinline__ ushort f2b(float f) {
  uint u = __float_as_uint(f);
  u += 0x7FFFu + ((u >> 16) & 1u);
  return (ushort)(u >> 16);
}
static __device__ __forceinline__ float b2f(ushort v) {
  return __uint_as_float(((uint)v) << 16);
}

#if __has_builtin(__builtin_amdgcn_fdot2)
#define DOT2(a, b, c) __builtin_amdgcn_fdot2((a), (b), (c), false)
#else
static __device__ __forceinline__ float DOT2(h2 a, h2 b, float c) {
  c = fmaf((float)a[0], (float)b[0], c);
  c = fmaf((float)a[1], (float)b[1], c);
  return c;
}
#endif

// -------- fused: node MLP + P/V/S1 bf16 production + dst histogram --------
__global__ __launch_bounds__(256) void prep(
    const float* __restrict__ ns, const float* __restrict__ nsv,
    const float* __restrict__ W1, const float* __restrict__ b1,
    const float* __restrict__ W2, const float* __restrict__ b2,
    ushort* __restrict__ Pb, ushort* __restrict__ Vb, ushort* __restrict__ S1b,
    const int* __restrict__ edges, int* __restrict__ cnt) {
  __shared__ float in_s[TM][NS];
  __shared__ float hid_s[TM][NS];

  if (blockIdx.x >= MLP_BLOCKS) {
    const int e = (blockIdx.x - MLP_BLOCKS) * 256 + threadIdx.x;
    if (e < NEDGES) atomicAdd(&cnt[edges[2 * e + 1]], 1);
    return;
  }

  const int t = threadIdx.x;
  const int n0 = blockIdx.x * TM;
  {
    const float4* src4 = (const float4*)(ns + (size_t)n0 * NS);
    float4* dst4 = (float4*)in_s;
    for (int idx = t; idx < TM * NS / 4; idx += 256) dst4[idx] = src4[idx];
  }
  __syncthreads();
  const int j = t & 127;
  const int half = t >> 7;
  {
    float acc[16];
#pragma unroll
    for (int m = 0; m < 16; ++m) acc[m] = b1[j];
    for (int k = 0; k < NS; k += 4) {
      const float w0 = W1[(k + 0) * NS + j];
      const float w1 = W1[(k + 1) * NS + j];
      const float w2 = W1[(k + 2) * NS + j];
      const float w3 = W1[(k + 3) * NS + j];
#pragma unroll
      for (int m = 0; m < 16; ++m) {
        const float4 iv = *(const float4*)&in_s[half * 16 + m][k];
        acc[m] = fmaf(iv.x, w0, acc[m]);
        acc[m] = fmaf(iv.y, w1, acc[m]);
        acc[m] = fmaf(iv.z, w2, acc[m]);
        acc[m] = fmaf(iv.w, w3, acc[m]);
      }
    }
#pragma unroll
    for (int m = 0; m < 16; ++m) {
      const float a = acc[m];
      hid_s[half * 16 + m][j] = a / (1.0f + __expf(-a));
    }
  }
  __syncthreads();
  {
    float o0[16], o1[16], o2[16];
    const float bb0 = b2[j], bb1 = b2[j + NS], bb2 = b2[j + 2 * NS];
#pragma unroll
    for (int m = 0; m < 16; ++m) { o0[m] = bb0; o1[m] = bb1; o2[m] = bb2; }
    for (int k = 0; k < NS; k += 4) {
      float wa[4], wb[4], wc[4];
#pragma unroll
      for (int kk = 0; kk < 4; ++kk) {
        wa[kk] = W2[(k + kk) * FW + j];
        wb[kk] = W2[(k + kk) * FW + j + NS];
        wc[kk] = W2[(k + kk) * FW + j + 2 * NS];
      }
#pragma unroll
      for (int m = 0; m < 16; ++m) {
        const float4 hv = *(const float4*)&hid_s[half * 16 + m][k];
        o0[m] = fmaf(hv.x, wa[0], o0[m]); o0[m] = fmaf(hv.y, wa[1], o0[m]);
        o0[m] = fmaf(hv.z, wa[2], o0[m]); o0[m] = fmaf(hv.w, wa[3], o0[m]);
        o1[m] = fmaf(hv.x, wb[0], o1[m]); o1[m] = fmaf(hv.y, wb[1], o1[m]);
        o1[m] = fmaf(hv.z, wb[2], o1[m]); o1[m] = fmaf(hv.w, wb[3], o1[m]);
        o2[m] = fmaf(hv.x, wc[0], o2[m]); o2[m] = fmaf(hv.y, wc[1], o2[m]);
        o2[m] = fmaf(hv.z, wc[2], o2[m]); o2[m] = fmaf(hv.w, wc[3], o2[m]);
      }
    }
#pragma unroll
    for (int m = 0; m < 16; ++m) {
      const int n = n0 + half * 16 + m;
      const float nsval = in_s[half * 16 + m][j];
      Pb[(size_t)n * NS + j]  = f2b(nsval * o2[m]);
      S1b[(size_t)n * NS + j] = f2b(o1[m]);
      const float* __restrict__ nvp = nsv + (size_t)n * 3 * NS;
      Vb[(size_t)n * 3 * NS + j]          = f2b(nvp[j] * o0[m]);
      Vb[(size_t)n * 3 * NS + NS + j]     = f2b(nvp[NS + j] * o0[m]);
      Vb[(size_t)n * 3 * NS + 2 * NS + j] = f2b(nvp[2 * NS + j] * o0[m]);
    }
  }
}

__global__ __launch_bounds__(256) void zero_cnt(int* __restrict__ cnt) {
  const int i = blockIdx.x * 256 + threadIdx.x;
  if (i < NNODES) cnt[i] = 0;
}

__global__ __launch_bounds__(1024) void scan_counts(const int* __restrict__ cnt,
                                                    int* __restrict__ offsets,
                                                    int* __restrict__ cursor) {
  __shared__ int psum[1024];
  const int t = threadIdx.x;
  const int base = t * 20;
  int local[20];
  int s = 0;
#pragma unroll
  for (int k = 0; k < 20; ++k) {
    const int idx = base + k;
    const int v = (idx < NNODES) ? cnt[idx] : 0;
    local[k] = s;
    s += v;
  }
  psum[t] = s;
  __syncthreads();
  for (int off = 1; off < 1024; off <<= 1) {
    const int v = (t >= off) ? psum[t - off] : 0;
    __syncthreads();
    psum[t] += v;
    __syncthreads();
  }
  const int pre = (t > 0) ? psum[t - 1] : 0;
#pragma unroll
  for (int k = 0; k < 20; ++k) {
    const int idx = base + k;
    if (idx < NNODES) {
      offsets[idx] = pre + local[k];
      cursor[idx] = pre + local[k];
    }
  }
  if (t == 1023) offsets[NNODES] = psum[1023];
}

// -------- scatter: 64 B sorted records {src, cut, env0..2, pad, f16(cut*es)[20]} --------
__global__ __launch_bounds__(256) void scatter_edges(
    const int* __restrict__ edges, const float* __restrict__ edge_distance,
    const float* __restrict__ edge_vector, const float* __restrict__ edge_state,
    int* __restrict__ cursor, uint* __restrict__ rec) {
  const int e = blockIdx.x * 256 + threadIdx.x;
  if (e >= NEDGES) return;
  const int src = edges[2 * e];
  const int dst = edges[2 * e + 1];
  const int pos = atomicAdd(&cursor[dst], 1);

  const float d = edge_distance[e];
  const float cut = (d < CUT) ? 0.5f * (__cosf(PI_F * d * (1.0f / CUT)) + 1.0f) : 0.0f;
  const float ev0 = edge_vector[3 * e + 0];
  const float ev1 = edge_vector[3 * e + 1];
  const float ev2 = edge_vector[3 * e + 2];
  const float inv = 1.0f / fmaxf(sqrtf(ev0 * ev0 + ev1 * ev1 + ev2 * ev2), 1e-12f);

  uint* __restrict__ r = rec + (size_t)pos * 16;
  r[0] = (uint)src;
  r[1] = __float_as_uint(cut);
  r[2] = __float_as_uint(ev0 * inv);
  r[3] = __float_as_uint(ev1 * inv);
  r[4] = __float_as_uint(ev2 * inv);
  r[5] = 0u;
  const float* __restrict__ esp = edge_state + (size_t)e * ESZ;
#pragma unroll
  for (int k = 0; k < 10; ++k) {
    union { h2 h; uint u; } cv;
    cv.h[0] = (_Float16)(cut * esp[2 * k]);
    cv.h[1] = (_Float16)(cut * esp[2 * k + 1]);
    r[6 + k] = cv.u;
  }
}

// -------- per-dst accumulation: packed-f16 dot2 filter + bf16 node gathers --------
__global__ __launch_bounds__(128) void accum(
    const uint4* __restrict__ rec, const int* __restrict__ offsets,
    const float* __restrict__ Wf, const float* __restrict__ bf,
    const ushort* __restrict__ Pb, const ushort* __restrict__ Vb,
    const ushort* __restrict__ S1b, const float* __restrict__ ns,
    const float* __restrict__ nsv, float* __restrict__ out0,
    float* __restrict__ out1) {
  const int n = blockIdx.x;
  const int j = threadIdx.x;
  const int beg = offsets[n];
  const int end = offsets[n + 1];

  // W_filter columns as packed f16 pairs: 30 regs, register-resident
  h2 wf0p[10], wf1p[10], wf2p[10];
#pragma unroll
  for (int k = 0; k < 10; ++k) {
    wf0p[k][0] = (_Float16)Wf[(2 * k) * FW + j];
    wf0p[k][1] = (_Float16)Wf[(2 * k + 1) * FW + j];
    wf1p[k][0] = (_Float16)Wf[(2 * k) * FW + j + NS];
    wf1p[k][1] = (_Float16)Wf[(2 * k + 1) * FW + j + NS];
    wf2p[k][0] = (_Float16)Wf[(2 * k) * FW + j + 2 * NS];
    wf2p[k][1] = (_Float16)Wf[(2 * k + 1) * FW + j + 2 * NS];
  }
  const float bf0 = bf[j], bf1 = bf[j + NS], bf2 = bf[j + 2 * NS];

  float accs = 0.0f, av0 = 0.0f, av1 = 0.0f, av2 = 0.0f;

#pragma unroll 2
  for (int i = beg; i < end; ++i) {
    const uint4 ra = rec[(size_t)i * 4 + 0];  // src, cut, env0, env1
    const uint4 rb = rec[(size_t)i * 4 + 1];  // env2, pad, es01, es23
    const uint4 rc = rec[(size_t)i * 4 + 2];  // es4..11
    const uint4 rd = rec[(size_t)i * 4 + 3];  // es12..19
    const int src = __builtin_amdgcn_readfirstlane((int)ra.x);
    const float cut  = __uint_as_float(ra.y);
    const float env0 = __uint_as_float(ra.z);
    const float env1 = __uint_as_float(ra.w);
    const float env2 = __uint_as_float(rb.x);

    float fw0 = cut * bf0, fw1 = cut * bf1, fw2 = cut * bf2;
    const uint ew[10] = {rb.z, rb.w, rc.x, rc.y, rc.z, rc.w, rd.x, rd.y, rd.z, rd.w};
#pragma unroll
    for (int k = 0; k < 10; ++k) {
      union { uint u; h2 h; } cv;
      cv.u = ew[k];
      fw0 = DOT2(cv.h, wf0p[k], fw0);
      fw1 = DOT2(cv.h, wf1p[k], fw1);
      fw2 = DOT2(cv.h, wf2p[k], fw2);
    }

    const float P  = b2f(Pb[(size_t)src * NS + j]);
    const float S1 = b2f(S1b[(size_t)src * NS + j]);
    const ushort* __restrict__ vp = Vb + (size_t)src * 3 * NS + j;
    const float V0 = b2f(vp[0]);
    const float V1 = b2f(vp[NS]);
    const float V2 = b2f(vp[2 * NS]);

    accs = fmaf(P, fw2, accs);
    const float s1fw = S1 * fw1;
    av0 = fmaf(V0, fw0, av0); av0 = fmaf(env0, s1fw, av0);
    av1 = fmaf(V1, fw0, av1); av1 = fmaf(env1, s1fw, av1);
    av2 = fmaf(V2, fw0, av2); av2 = fmaf(env2, s1fw, av2);
  }

  out0[(size_t)n * NS + j] = ns[(size_t)n * NS + j] + accs;
  float* __restrict__ o1 = out1 + (size_t)n * 3 * NS;
  const float* __restrict__ nvd = nsv + (size_t)n * 3 * NS;
  o1[j] = nvd[j] + av0;
  o1[NS + j] = nvd[NS + j] + av1;
  o1[2 * NS + j] = nvd[2 * NS + j] + av2;
}

extern "C" void kernel_launch(void* const* d_in, const int* in_sizes, int n_in,
                              void* d_out, int out_size, void* d_ws, size_t ws_size,
                              hipStream_t stream) {
  const float* node_state_scalar = (const float*)d_in[0];
  const float* node_state_vector = (const float*)d_in[1];
  const float* edge_state        = (const float*)d_in[2];
  const float* edge_vector       = (const float*)d_in[3];
  const float* edge_distance     = (const float*)d_in[4];
  const int*   edges             = (const int*)d_in[5];
  const float* W_filter          = (const float*)d_in[6];
  const float* b_filter          = (const float*)d_in[7];
  const float* W1                = (const float*)d_in[8];
  const float* b1                = (const float*)d_in[9];
  const float* W2                = (const float*)d_in[10];
  const float* b2                = (const float*)d_in[11];

  float* out0 = (float*)d_out;
  float* out1 = (float*)d_out + (size_t)NNODES * NS;

  // workspace layout (~67 MB)
  char* w = (char*)d_ws;
  ushort* Pb  = (ushort*)w;  w += (size_t)NNODES * NS * 2;
  ushort* S1b = (ushort*)w;  w += (size_t)NNODES * NS * 2;
  ushort* Vb  = (ushort*)w;  w += (size_t)NNODES * 3 * NS * 2;
  uint*   rec = (uint*)w;    w += (size_t)NEDGES * 64;
  int* offsets = (int*)w;    w += (NNODES + 1) * 4;
  int* cursor  = (int*)w;    w += NNODES * 4;
  int* cnt     = (int*)w;

  zero_cnt<<<(NNODES + 255) / 256, 256, 0, stream>>>(cnt);
  prep<<<MLP_BLOCKS + HIST_BLOCKS, 256, 0, stream>>>(
      node_state_scalar, node_state_vector, W1, b1, W2, b2,
      Pb, Vb, S1b, edges, cnt);
  scan_counts<<<1, 1024, 0, stream>>>(cnt, offsets, cursor);
  scatter_edges<<<(NEDGES + 255) / 256, 256, 0, stream>>>(
      edges, edge_distance, edge_vector, edge_state, cursor, rec);
  accum<<<NNODES, 128, 0, stream>>>((const uint4*)rec, offsets, W_filter, b_filter,
                                    Pb, Vb, S1b, node_state_scalar,
                                    node_state_vector, out0, out1);
}